// Round 13
// baseline (56066.644 us; speedup 1.0000x reference)
//
#include <hip/hip_runtime.h>
#include <stdint.h>
#include <math.h>

// Round 13 = R7/R11 pipeline; conv1 tree T4: ONE f32 accumulator, taps in
// row-major (ky,kx) order, ci innermost — the summation order produced by
// XLA-CPU (NHWC im2col + Eigen gemm, k=(ky,kx,ci) sequential w/ FMA; FMA ==
// plain add here since products are exactly ±x) and by a direct
// for-ky/for-kx/for-ci loop translation with a float32 accumulator.
// Padded taps add exact 0 (skip is bit-equivalent). Downstream layers are
// integer-exact and decision-identical in any faithful arithmetic — verbatim R7.

// ---------- weight binarization ----------
__global__ void kw_sign(const float* __restrict__ w, int8_t* __restrict__ s, int n) {
    int i = blockIdx.x * 256 + threadIdx.x;
    if (i >= n) return;
    float v = w[i];
    s[i] = (int8_t)((v > 0.f) - (v < 0.f));
}

// ---------- conv1 (T4): sequential f32, (ky,kx) outer, ci inner ----------
__global__ void k1_conv(const float* __restrict__ x, const float* __restrict__ w1,
                        float* __restrict__ out, int grp) {
    int hw = blockIdx.x * 64 + threadIdx.x;      // 0..1023
    int cg = blockIdx.y;                         // 0..7
    int n  = blockIdx.z;
    int co = grp * 8 + cg;
    int y = hw >> 5, x0 = hw & 31;
    const float* ip0 = x + ((size_t)n * 3 + 0) * 1024;
    const float* ip1 = x + ((size_t)n * 3 + 1) * 1024;
    const float* ip2 = x + ((size_t)n * 3 + 2) * 1024;
    const float* wp  = w1 + (size_t)co * 27;     // OIHW: (ci,ky,kx)
    float acc = 0.f;
    for (int ky = 0; ky < 3; ++ky) {
        int yy = y + ky - 1;
        if (yy < 0 || yy > 31) continue;         // padded row: exact zero taps
        for (int kx = 0; kx < 3; ++kx) {
            int xc = x0 + kx - 1;
            if (xc < 0 || xc > 31) continue;     // padded col: exact zero tap
            int sp = yy * 32 + xc;
            int wk = ky * 3 + kx;
            float w0 = wp[wk], w1v = wp[9 + wk], w2 = wp[18 + wk];
            // ci innermost, each added directly into the single f32 accumulator
            acc += (w0  > 0.f) ? ip0[sp] : ((w0  < 0.f) ? -ip0[sp] : 0.f);
            acc += (w1v > 0.f) ? ip1[sp] : ((w1v < 0.f) ? -ip1[sp] : 0.f);
            acc += (w2  > 0.f) ? ip2[sp] : ((w2  < 0.f) ? -ip2[sp] : 0.f);
        }
    }
    out[((size_t)n * 8 + cg) * 1024 + hw] = acc;
}

// ---------- L1 stats: exact f64 sums -> f32 mu / f32 rsqrt (decision-safe) ----------
__device__ __forceinline__ float ld1(const float* v, int cg, int e) {
    return v[((size_t)(e >> 10) * 8 + cg) * 1024 + (e & 1023)];
}

__global__ void k1_stats(const float* __restrict__ v, float* __restrict__ muF,
                         float* __restrict__ rF, int grp, int N) {
    int cg = blockIdx.x;
    __shared__ double sh[256], sh2[256];
    double s = 0.0, s2 = 0.0;
    int M = N * 1024;
    for (int m = threadIdx.x; m < M; m += 256) {
        double t = (double)ld1(v, cg, m);
        s += t; s2 += t * t;
    }
    sh[threadIdx.x] = s; sh2[threadIdx.x] = s2;
    __syncthreads();
    for (int o = 128; o > 0; o >>= 1) {
        if ((int)threadIdx.x < o) { sh[threadIdx.x] += sh[threadIdx.x + o]; sh2[threadIdx.x] += sh2[threadIdx.x + o]; }
        __syncthreads();
    }
    if (threadIdx.x == 0) {
        double mean = sh[0] / M;
        double var  = sh2[0] / M - mean * mean;
        if (var < 0.0) var = 0.0;
        muF[grp * 8 + cg] = (float)mean;
        rF[grp * 8 + cg]  = 1.0f / sqrtf((float)var + 1e-5f);
    }
}

// f32 bn sign: t = ((v - mu)*r)*g + b, strict trichotomy
__global__ void k1_sign(const float* __restrict__ v, const float* __restrict__ muF,
                        const float* __restrict__ rF, const float* __restrict__ g,
                        const float* __restrict__ b, int8_t* __restrict__ sgn, int grp) {
    int hw = blockIdx.x * 256 + threadIdx.x;
    if (hw >= 1024) return;
    int cg = blockIdx.y, n = blockIdx.z;
    int c = grp * 8 + cg;
    float d  = v[((size_t)n * 8 + cg) * 1024 + hw] - muF[c];
    float t  = (d * rF[c]) * g[c] + b[c];
    sgn[((size_t)n * 64 + c) * 1024 + hw] = (int8_t)((t > 0.f) - (t < 0.f));
}

// ---------- binary convs (exact integers) ----------
__device__ __forceinline__ int conv3x3_at(const int8_t* __restrict__ in,
                                          const int8_t* __restrict__ wc,
                                          int Ci, int H, int W, int n, int co, int y, int x) {
    int acc = 0;
    for (int ci = 0; ci < Ci; ++ci) {
        const int8_t* ip = in + ((size_t)n * Ci + ci) * H * W;
        const int8_t* wp = wc + ((size_t)co * Ci + ci) * 9;
        for (int dy = -1; dy <= 1; ++dy) {
            int yy = y + dy;
            if (yy < 0 || yy >= H) continue;
            for (int dx = -1; dx <= 1; ++dx) {
                int xc = x + dx;
                if (xc < 0 || xc >= W) continue;
                acc += (int)ip[yy * W + xc] * (int)wp[(dy + 1) * 3 + (dx + 1)];
            }
        }
    }
    return acc;
}

__global__ void k2_conv(const int8_t* __restrict__ in, const int8_t* __restrict__ wc,
                        int16_t* __restrict__ out, int Ci, int Co, int H, int W) {
    int hw = blockIdx.x * 64 + threadIdx.x;
    if (hw >= H * W) return;
    int co = blockIdx.y, n = blockIdx.z;
    int y = hw / W, x = hw % W;
    out[((size_t)n * Co + co) * H * W + hw] = (int16_t)conv3x3_at(in, wc, Ci, H, W, n, co, y, x);
}

__global__ void k2_conv_pool(const int8_t* __restrict__ in, const int8_t* __restrict__ wc,
                             int16_t* __restrict__ out, int Ci, int Co, int H, int W) {
    int Ho = H >> 1, Wo = W >> 1;
    int hw = blockIdx.x * 64 + threadIdx.x;
    if (hw >= Ho * Wo) return;
    int co = blockIdx.y, n = blockIdx.z;
    int yo = hw / Wo, xo = hw % Wo;
    int best = -(1 << 30);
    for (int dy = 0; dy < 2; ++dy)
        for (int dx = 0; dx < 2; ++dx) {
            int v = conv3x3_at(in, wc, Ci, H, W, n, co, 2 * yo + dy, 2 * xo + dx);
            if (v > best) best = v;
        }
    out[((size_t)n * Co + co) * Ho * Wo + hw] = (int16_t)best;
}

__global__ void k2_stats(const int16_t* __restrict__ v, int N, int C, int HW,
                         const float* __restrict__ g, const float* __restrict__ b,
                         double* __restrict__ mu, double* __restrict__ Ad,
                         double* __restrict__ Bd) {
    int c = blockIdx.x;
    __shared__ double sh[256], sh2[256];
    double s = 0.0, s2 = 0.0;
    int M = N * HW;
    for (int m = threadIdx.x; m < M; m += 256) {
        double t = (double)v[((size_t)(m / HW) * C + c) * HW + (m % HW)];
        s += t; s2 += t * t;
    }
    sh[threadIdx.x] = s; sh2[threadIdx.x] = s2;
    __syncthreads();
    for (int o = 128; o > 0; o >>= 1) {
        if ((int)threadIdx.x < o) { sh[threadIdx.x] += sh[threadIdx.x + o]; sh2[threadIdx.x] += sh2[threadIdx.x + o]; }
        __syncthreads();
    }
    if (threadIdx.x == 0) {
        double mean = sh[0] / M;
        double var  = sh2[0] / M - mean * mean;
        if (var < 0.0) var = 0.0;
        mu[c] = mean;
        Ad[c] = (g ? (double)g[c] : 1.0) / sqrt(var + 1e-5);
        Bd[c] = b ? (double)b[c] : 0.0;
    }
}

__global__ void k2_sign(const int16_t* __restrict__ v, const double* __restrict__ mu,
                        const double* __restrict__ Ad, const double* __restrict__ Bd,
                        int8_t* __restrict__ out, int C, int HW) {
    int hw = blockIdx.x * 256 + threadIdx.x;
    if (hw >= HW) return;
    int c = blockIdx.y, n = blockIdx.z;
    size_t i = ((size_t)n * C + c) * HW + hw;
    double t = ((double)v[i] - mu[c]) * Ad[c] + Bd[c];
    out[i] = (int8_t)((t > 0.0) - (t < 0.0));
}

// ---------- binary FC ----------
__global__ void k3_fc(const int8_t* __restrict__ a, const int8_t* __restrict__ w,
                      int* __restrict__ out, int K, int O) {
    int o = blockIdx.x * 64 + threadIdx.x;
    if (o >= O) return;
    int n = blockIdx.y;
    const int8_t* ar = a + (size_t)n * K;
    const int8_t* wr = w + (size_t)o * K;
    int acc = 0;
    for (int k = 0; k < K; ++k) acc += (int)ar[k] * (int)wr[k];
    out[(size_t)n * O + o] = acc;
}

__global__ void k3_stats(const int* __restrict__ v, int N, int C,
                         const float* __restrict__ g, const float* __restrict__ b,
                         double* __restrict__ mu, double* __restrict__ Ad,
                         double* __restrict__ Bd) {
    int c = blockIdx.x;
    __shared__ double sh[256], sh2[256];
    double s = 0.0, s2 = 0.0;
    for (int n = threadIdx.x; n < N; n += 256) {
        double t = (double)v[(size_t)n * C + c];
        s += t; s2 += t * t;
    }
    sh[threadIdx.x] = s; sh2[threadIdx.x] = s2;
    __syncthreads();
    for (int o = 128; o > 0; o >>= 1) {
        if ((int)threadIdx.x < o) { sh[threadIdx.x] += sh[threadIdx.x + o]; sh2[threadIdx.x] += sh2[threadIdx.x + o]; }
        __syncthreads();
    }
    if (threadIdx.x == 0) {
        double mean = sh[0] / N;
        double var  = sh2[0] / N - mean * mean;
        if (var < 0.0) var = 0.0;
        mu[c] = mean;
        Ad[c] = (g ? (double)g[c] : 1.0) / sqrt(var + 1e-5);
        Bd[c] = b ? (double)b[c] : 0.0;
    }
}

__global__ void k3_sign(const int* __restrict__ v, const double* __restrict__ mu,
                        const double* __restrict__ Ad, const double* __restrict__ Bd,
                        int8_t* __restrict__ out, int C) {
    int c = blockIdx.x * 256 + threadIdx.x;
    if (c >= C) return;
    int n = blockIdx.y;
    double t = ((double)v[(size_t)n * C + c] - mu[c]) * Ad[c] + Bd[c];
    out[(size_t)n * C + c] = (int8_t)((t > 0.0) - (t < 0.0));
}

__global__ void k4_out(const int* __restrict__ v, const double* __restrict__ mu,
                       const double* __restrict__ Ad, float* __restrict__ out, int N) {
    int n = blockIdx.x * 256 + threadIdx.x;
    if (n >= N) return;
    double z[10];
    double mx = -1e300;
    for (int o = 0; o < 10; ++o) {
        z[o] = ((double)v[n * 10 + o] - mu[o]) * Ad[o];
        if (z[o] > mx) mx = z[o];
    }
    double s = 0.0;
    for (int o = 0; o < 10; ++o) s += exp(z[o] - mx);
    double l = mx + log(s);
    for (int o = 0; o < 10; ++o) out[n * 10 + o] = (float)(z[o] - l);
}

// ---------------- host ----------------
extern "C" void kernel_launch(void* const* d_in, const int* in_sizes, int n_in,
                              void* d_out, int out_size, void* d_ws, size_t ws_size,
                              hipStream_t stream) {
    const int N = in_sizes[0] / (3 * 32 * 32);   // 512

    const float* x   = (const float*)d_in[0];
    const float* w1  = (const float*)d_in[1];
    const float* g1  = (const float*)d_in[2];
    const float* b1  = (const float*)d_in[3];
    const float* w2  = (const float*)d_in[4];
    const float* g2  = (const float*)d_in[5];
    const float* b2  = (const float*)d_in[6];
    const float* w3  = (const float*)d_in[7];
    const float* g3  = (const float*)d_in[8];
    const float* b3  = (const float*)d_in[9];
    const float* w4  = (const float*)d_in[10];
    const float* g4  = (const float*)d_in[11];
    const float* b4  = (const float*)d_in[12];
    const float* w5  = (const float*)d_in[13];
    const float* g5  = (const float*)d_in[14];
    const float* b5  = (const float*)d_in[15];
    const float* w6  = (const float*)d_in[16];
    const float* g6  = (const float*)d_in[17];
    const float* b6  = (const float*)d_in[18];
    const float* wf1 = (const float*)d_in[19];
    const float* gf1 = (const float*)d_in[20];
    const float* bf1 = (const float*)d_in[21];
    const float* wf2 = (const float*)d_in[22];
    const float* gf2 = (const float*)d_in[23];
    const float* bf2 = (const float*)d_in[24];
    const float* wf3 = (const float*)d_in[25];

    char* ws = (char*)d_ws;
    size_t off = 0;
    auto alloc = [&](size_t bytes) -> char* {
        char* p = ws + off;
        off = (off + bytes + 511) & ~(size_t)511;
        return p;
    };

    char* regA = alloc((size_t)N * 8 * 1024 * 8);     // 33.5 MB shared region
    float*   c1buf = (float*)regA;                     // conv1 group (f32), dead after L1
    int16_t* t3    = (int16_t*)regA;
    int16_t* t5    = (int16_t*)(regA + (size_t)N * 128 * 256 * 2);

    char* regB = alloc((size_t)N * 64 * 1024);
    int8_t* sgnA = (int8_t*)regB;
    int8_t* sgnC = (int8_t*)regB;
    int8_t* sgnD = (int8_t*)(regB + (size_t)N * 128 * 256);
    int8_t* sgnE = (int8_t*)(regB + (size_t)N * 128 * 256 + (size_t)N * 128 * 64);

    int16_t* t2    = (int16_t*)alloc((size_t)N * 64 * 256 * 2);
    int8_t*  sgnB  = (int8_t*)alloc((size_t)N * 64 * 256);
    int16_t* t4    = (int16_t*)alloc((size_t)N * 128 * 64 * 2);
    int16_t* t6    = (int16_t*)alloc((size_t)N * 256 * 16 * 2);
    int8_t*  sgnF0 = (int8_t*)alloc((size_t)N * 4096);
    int*     fc1   = (int*)alloc((size_t)N * 512 * 4);
    int8_t*  sgnF1 = (int8_t*)alloc((size_t)N * 512);
    int*     fc2   = (int*)alloc((size_t)N * 512 * 4);
    int8_t*  sgnF2 = (int8_t*)alloc((size_t)N * 512);
    int*     fc3   = (int*)alloc((size_t)N * 10 * 4);

    int8_t* wb2  = (int8_t*)alloc(64 * 64 * 9);
    int8_t* wb3  = (int8_t*)alloc(128 * 64 * 9);
    int8_t* wb4  = (int8_t*)alloc(128 * 128 * 9);
    int8_t* wb5  = (int8_t*)alloc(256 * 128 * 9);
    int8_t* wb6  = (int8_t*)alloc(256 * 256 * 9);
    int8_t* wbf1 = (int8_t*)alloc(512 * 4096);
    int8_t* wbf2 = (int8_t*)alloc(512 * 512);
    int8_t* wbf3 = (int8_t*)alloc(10 * 512);

    double* mu = (double*)alloc(512 * 8);
    double* Ad = (double*)alloc(512 * 8);
    double* Bd = (double*)alloc(512 * 8);
    float*  muF = (float*)alloc(64 * 4);
    float*  rF  = (float*)alloc(64 * 4);
    (void)ws_size;

    auto cdiv = [](int a, int b) { return (a + b - 1) / b; };

    kw_sign<<<cdiv(64 * 64 * 9, 256), 256, 0, stream>>>(w2, wb2, 64 * 64 * 9);
    kw_sign<<<cdiv(128 * 64 * 9, 256), 256, 0, stream>>>(w3, wb3, 128 * 64 * 9);
    kw_sign<<<cdiv(128 * 128 * 9, 256), 256, 0, stream>>>(w4, wb4, 128 * 128 * 9);
    kw_sign<<<cdiv(256 * 128 * 9, 256), 256, 0, stream>>>(w5, wb5, 256 * 128 * 9);
    kw_sign<<<cdiv(256 * 256 * 9, 256), 256, 0, stream>>>(w6, wb6, 256 * 256 * 9);
    kw_sign<<<cdiv(512 * 4096, 256), 256, 0, stream>>>(wf1, wbf1, 512 * 4096);
    kw_sign<<<cdiv(512 * 512, 256), 256, 0, stream>>>(wf2, wbf2, 512 * 512);
    kw_sign<<<cdiv(10 * 512, 256), 256, 0, stream>>>(wf3, wbf3, 10 * 512);

    // L1: T4 conv1 (f32 seq, taps outer, ci inner), f64->f32 mean, f32 sign
    for (int grp = 0; grp < 8; ++grp) {
        k1_conv<<<dim3(16, 8, N), 64, 0, stream>>>(x, w1, c1buf, grp);
        k1_stats<<<8, 256, 0, stream>>>(c1buf, muF, rF, grp, N);
        k1_sign<<<dim3(4, 8, N), 256, 0, stream>>>(c1buf, muF, rF, g1, b1, sgnA, grp);
    }

    // L2
    k2_conv_pool<<<dim3(cdiv(256, 64), 64, N), 64, 0, stream>>>(sgnA, wb2, t2, 64, 64, 32, 32);
    k2_stats<<<64, 256, 0, stream>>>(t2, N, 64, 256, g2, b2, mu, Ad, Bd);
    k2_sign<<<dim3(1, 64, N), 256, 0, stream>>>(t2, mu, Ad, Bd, sgnB, 64, 256);

    // L3
    k2_conv<<<dim3(cdiv(256, 64), 128, N), 64, 0, stream>>>(sgnB, wb3, t3, 64, 128, 16, 16);
    k2_stats<<<128, 256, 0, stream>>>(t3, N, 128, 256, g3, b3, mu, Ad, Bd);
    k2_sign<<<dim3(1, 128, N), 256, 0, stream>>>(t3, mu, Ad, Bd, sgnC, 128, 256);

    // L4
    k2_conv_pool<<<dim3(cdiv(64, 64), 128, N), 64, 0, stream>>>(sgnC, wb4, t4, 128, 128, 16, 16);
    k2_stats<<<128, 256, 0, stream>>>(t4, N, 128, 64, g4, b4, mu, Ad, Bd);
    k2_sign<<<dim3(1, 128, N), 256, 0, stream>>>(t4, mu, Ad, Bd, sgnD, 128, 64);

    // L5
    k2_conv<<<dim3(cdiv(64, 64), 256, N), 64, 0, stream>>>(sgnD, wb5, t5, 128, 256, 8, 8);
    k2_stats<<<256, 256, 0, stream>>>(t5, N, 256, 64, g5, b5, mu, Ad, Bd);
    k2_sign<<<dim3(1, 256, N), 256, 0, stream>>>(t5, mu, Ad, Bd, sgnE, 256, 64);

    // L6
    k2_conv_pool<<<dim3(cdiv(16, 64), 256, N), 64, 0, stream>>>(sgnE, wb6, t6, 256, 256, 8, 8);
    k2_stats<<<256, 256, 0, stream>>>(t6, N, 256, 16, g6, b6, mu, Ad, Bd);
    k2_sign<<<dim3(1, 256, N), 256, 0, stream>>>(t6, mu, Ad, Bd, sgnF0, 256, 16);

    // FC1
    k3_fc<<<dim3(cdiv(512, 64), N), 64, 0, stream>>>(sgnF0, wbf1, fc1, 4096, 512);
    k3_stats<<<512, 256, 0, stream>>>(fc1, N, 512, gf1, bf1, mu, Ad, Bd);
    k3_sign<<<dim3(cdiv(512, 256), N), 256, 0, stream>>>(fc1, mu, Ad, Bd, sgnF1, 512);

    // FC2
    k3_fc<<<dim3(cdiv(512, 64), N), 64, 0, stream>>>(sgnF1, wbf2, fc2, 512, 512);
    k3_stats<<<512, 256, 0, stream>>>(fc2, N, 512, gf2, bf2, mu, Ad, Bd);
    k3_sign<<<dim3(cdiv(512, 256), N), 256, 0, stream>>>(fc2, mu, Ad, Bd, sgnF2, 512);

    // FC3 + bn(no affine) + log_softmax
    k3_fc<<<dim3(cdiv(10, 64), N), 64, 0, stream>>>(sgnF2, wbf3, fc3, 512, 10);
    k3_stats<<<10, 256, 0, stream>>>(fc3, N, 10, nullptr, nullptr, mu, Ad, Bd);
    k4_out<<<cdiv(N, 256), 256, 0, stream>>>(fc3, mu, Ad, (float*)d_out, N);
}